// Round 15
// baseline (94.325 us; speedup 1.0000x reference)
//
#include <hip/hip_runtime.h>
#include <hip/hip_fp16.h>
#include <math.h>

#define D_DET 512
#define N_ANG 180
#define S_IMG 512
#define NPIX  (S_IMG * S_IMG)
#define T_MAX 63                 // ramp tap truncation
#define NREP  4                  // DIAGNOSTIC: in-kernel repeat to surface counters

typedef _Float16 half2v __attribute__((ext_vector_type(2)));

__device__ __constant__ float kPI = 3.14159265358979323846f;

__device__ __forceinline__ half2v pack_weights(float a, float b) {
    return __builtin_bit_cast(half2v, __builtin_amdgcn_cvt_pkrtz(a, b));
}

// ---------------------------------------------------------------------------
// Stage 1: ramp filter (R13 verbatim): truncated symmetric convolution,
// angle-quad blocks, float4 input loads. Grid: 90 blocks x 512 threads.
// Output word (a*512+d)*2+bc = packed fp16 (xf[d], xf[d+1]), xf[512]=0.
// ---------------------------------------------------------------------------
__global__ __launch_bounds__(512) void ramp_filter_kernel(
    const float* __restrict__ x, unsigned* __restrict__ xfh) {
    __shared__ float rp[4][640];
    __shared__ float xf[4][D_DET + 1];

    const int blk = blockIdx.x;
    const int bc  = blk / 45;            // 0..1
    const int a0  = (blk % 45) * 4;
    const int d   = threadIdx.x;

    float4 q = *(const float4*)(x + (bc * D_DET + d) * N_ANG + a0);
    rp[0][64 + d] = q.x;
    rp[1][64 + d] = q.y;
    rp[2][64 + d] = q.z;
    rp[3][64 + d] = q.w;
    if (d < 64) {
        #pragma unroll
        for (int r = 0; r < 4; ++r) { rp[r][d] = 0.0f; rp[r][576 + d] = 0.0f; }
    }
    if (d < 4) xf[d][D_DET] = 0.0f;
    __syncthreads();

    constexpr float PI_ = 3.14159265358979323846f;
    #pragma unroll
    for (int r = 0; r < 4; ++r) {
        const float* rm = &rp[r][64 + d];
        float acc = 0.5f * rm[0];
        #pragma unroll
        for (int k = 0; k < (T_MAX + 1) / 2; ++k) {
            const int   t = 2 * k + 1;
            const float h = -2.0f / (PI_ * PI_ * (float)(t * t));
            acc = fmaf(rm[-t] + rm[t], h, acc);
        }
        xf[r][d] = acc;
    }
    __syncthreads();

    #pragma unroll
    for (int r = 0; r < 4; ++r) {
        const unsigned lo = __half_as_ushort(__float2half_rn(xf[r][d]));
        const unsigned hi = __half_as_ushort(__float2half_rn(xf[r][d + 1]));
        xfh[((a0 + r) * D_DET + d) * 2 + bc] = (hi << 16) | lo;
    }
}

// ---------------------------------------------------------------------------
// Stage 2: backprojection — R13 structure EXACTLY, but the angle loop runs
// NREP=4x inside the kernel (DIAGNOSTIC: one ~104 us dispatch so its PMC
// row tops the fill dispatches). Output identical: each rep restarts the
// accumulators from a laundered zero (asm "+v" -> no CSE across reps,
// "memory" clobber -> loads really re-issue), only the last rep is written;
// earlier reps are kept live via asm sinks (no DCE).
// ---------------------------------------------------------------------------
__global__ __launch_bounds__(256) void backproj_kernel(
    const uint2* __restrict__ xfh, float* __restrict__ out) {
    __shared__ float2 trig[N_ANG];
    const int tid = threadIdx.x;
    if (tid < N_ANG) {
        float th = (float)tid * (kPI / 180.0f);
        float s, c;
        sincosf(th, &s, &c);
        trig[tid] = make_float2(c * 255.5f, s * 255.5f);
    }
    __syncthreads();

    const int bi   = blockIdx.x >> 5;
    const int bj   = blockIdx.x & 31;
    const int wave = tid >> 6;
    const int lane = tid & 63;
    const int i = (bi << 4) + ((wave >> 1) << 3) + (lane >> 3);
    const int j = (bj << 4) + ((wave & 1) << 3) + (lane & 7);

    const float xP = (float)j * (2.0f / 511.0f) - 1.0f;
    const float yP = (float)i * (2.0f / 511.0f) - 1.0f;
    const float m  = xP * xP + yP * yP;
    const int  p   = i * S_IMG + j;

    if (!__any(m <= 1.0f)) {
        out[p]        = 0.0f;
        out[NPIX + p] = 0.0f;
        return;
    }

    float a0 = 0.0f, a1 = 0.0f;
    #pragma unroll 1
    for (int rep = 0; rep < NREP; ++rep) {
        float z = 0.0f;
        asm volatile("" : "+v"(z));      // launder 0: unique chain root per rep
        float b0 = z, b1 = z;
        #pragma unroll 4
        for (int a = 0; a < N_ANG; ++a) {
            float2 t  = trig[a];
            float pc  = fminf(fmaxf(fmaf(xP, t.x, fmaf(yP, -t.y, 255.5f)), 0.0f), 511.0f);
            float fi  = floorf(pc);
            float w   = pc - fi;
            half2v hw = pack_weights(1.0f - w, w);
            uint2  g  = xfh[(a << 9) + (int)fi];
            b0 = __builtin_amdgcn_fdot2(hw, __builtin_bit_cast(half2v, g.x), b0, false);
            b1 = __builtin_amdgcn_fdot2(hw, __builtin_bit_cast(half2v, g.y), b1, false);
        }
        a0 = b0; a1 = b1;
        // keep this rep's result live; memory clobber forces real re-loads
        asm volatile("" : : "v"(a0), "v"(a1) : "memory");
    }

    const float msk = (m <= 1.0f) ? (kPI / (2.0f * (float)N_ANG)) : 0.0f;
    out[p]        = a0 * msk;
    out[NPIX + p] = a1 * msk;
}

// ---------------------------------------------------------------------------
extern "C" void kernel_launch(void* const* d_in, const int* in_sizes, int n_in,
                              void* d_out, int out_size, void* d_ws, size_t ws_size,
                              hipStream_t stream) {
    const float* x   = (const float*)d_in[0];
    float*       out = (float*)d_out;
    unsigned*    xfh = (unsigned*)d_ws;  // 737,280 B

    ramp_filter_kernel<<<90, 512, 0, stream>>>(x, xfh);
    backproj_kernel<<<1024, 256, 0, stream>>>((const uint2*)xfh, out);
}

// Round 16
// 32.780 us; speedup vs baseline: 2.8775x; 2.8775x over previous
//
#include <hip/hip_runtime.h>
#include <hip/hip_fp16.h>
#include <math.h>

#define D_DET 512
#define N_ANG 180
#define S_IMG 512
#define NPIX  (S_IMG * S_IMG)
#define T_MAX 63                 // ramp tap truncation

typedef _Float16 half2v __attribute__((ext_vector_type(2)));

__device__ __constant__ float kPI = 3.14159265358979323846f;

__device__ __forceinline__ half2v pack_w1(float w) {
    return __builtin_bit_cast(half2v, __builtin_amdgcn_cvt_pkrtz(1.0f, w));
}

// ---------------------------------------------------------------------------
// Stage 1: ramp filter (R13 structure), output re-packed as (f, DELTA):
//   word (a*512+d)*2+bc = fp16x2 (xf[d], xf[d+1]-xf[d]),  xf[512]=0.
// Lerp in stage 2 becomes fdot2((1,w),(f,D)) = f + w*D  (saves the 1-w sub).
// Grid: 90 blocks = (bc, 4 angles) x 512 threads; float4 input loads.
// ---------------------------------------------------------------------------
__global__ __launch_bounds__(512) void ramp_filter_kernel(
    const float* __restrict__ x, unsigned* __restrict__ xfh) {
    __shared__ float rp[4][640];
    __shared__ float xf[4][D_DET + 1];

    const int blk = blockIdx.x;
    const int bc  = blk / 45;            // 0..1
    const int a0  = (blk % 45) * 4;
    const int d   = threadIdx.x;

    float4 q = *(const float4*)(x + (bc * D_DET + d) * N_ANG + a0);
    rp[0][64 + d] = q.x;
    rp[1][64 + d] = q.y;
    rp[2][64 + d] = q.z;
    rp[3][64 + d] = q.w;
    if (d < 64) {
        #pragma unroll
        for (int r = 0; r < 4; ++r) { rp[r][d] = 0.0f; rp[r][576 + d] = 0.0f; }
    }
    if (d < 4) xf[d][D_DET] = 0.0f;
    __syncthreads();

    constexpr float PI_ = 3.14159265358979323846f;
    #pragma unroll
    for (int r = 0; r < 4; ++r) {
        const float* rm = &rp[r][64 + d];
        float acc = 0.5f * rm[0];
        #pragma unroll
        for (int k = 0; k < (T_MAX + 1) / 2; ++k) {
            const int   t = 2 * k + 1;
            const float h = -2.0f / (PI_ * PI_ * (float)(t * t));
            acc = fmaf(rm[-t] + rm[t], h, acc);
        }
        xf[r][d] = acc;
    }
    __syncthreads();

    #pragma unroll
    for (int r = 0; r < 4; ++r) {
        const float f0 = xf[r][d];
        const float dl = xf[r][d + 1] - f0;
        const unsigned lo = __half_as_ushort(__float2half_rn(f0));
        const unsigned hi = __half_as_ushort(__float2half_rn(dl));
        xfh[((a0 + r) * D_DET + d) * 2 + bc] = (hi << 16) | lo;
    }
}

// ---------------------------------------------------------------------------
// Stage 2: backprojection, in-block angle split x2 + lean inner loop.
// Block = 512 threads: tid&255 -> pixel of a 16x16 tile (waves = 8x8
// patches), tid>>8 -> angle half (0..89 / 90..179). 1024 blocks x 8 waves
// = 32 waves/CU (2x R13 -- latency hiding), LDS float2 reduction at end.
// Inner loop (11 VALU): fma, fma, max, cvt_i32, fract, cvt_pkrtz(1,w),
// addr lshl_add, 2x fdot2 + uniform ds_read_b64 + 8B gather.
// Out-of-circle lanes get sanitized coords (0,0): pc=255.5 always in
// range -> no upper clamp needed (in-circle pc <= 511.0001 safe: row has
// 512 entries, pair at 511 = (f[511], -f[511])); v_max handles the -eps
// boundary case exactly like the old med3 (pc=0 -> w=0 -> f[0]).
// ---------------------------------------------------------------------------
__global__ __launch_bounds__(512) void backproj_kernel(
    const uint2* __restrict__ xfh, float* __restrict__ out) {
    __shared__ float2 trig[N_ANG];       // (cos*255.5, sin*255.5)
    __shared__ float2 red[256];          // half-1 partial sums
    const int tid = threadIdx.x;
    if (tid < N_ANG) {
        float th = (float)tid * (kPI / 180.0f);
        float s, c;
        sincosf(th, &s, &c);
        trig[tid] = make_float2(c * 255.5f, s * 255.5f);
    }
    __syncthreads();

    const int bi   = blockIdx.x >> 5;    // 32 i-tiles of 16
    const int bj   = blockIdx.x & 31;    // 32 j-tiles of 16
    const int half = tid >> 8;           // angle half
    const int sub  = (tid >> 6) & 3;     // wave within half
    const int lane = tid & 63;
    const int px   = tid & 255;
    const int i = (bi << 4) + ((sub >> 1) << 3) + (lane >> 3);
    const int j = (bj << 4) + ((sub & 1) << 3) + (lane & 7);

    const float xP = (float)j * (2.0f / 511.0f) - 1.0f;
    const float yP = (float)i * (2.0f / 511.0f) - 1.0f;
    const float m  = xP * xP + yP * yP;
    const bool inc = (m <= 1.0f);
    const float xS = inc ? xP : 0.0f;    // sanitize: out-circle -> pc=255.5
    const float yS = inc ? yP : 0.0f;

    float a0 = 0.0f, a1 = 0.0f;
    if (__any(inc)) {
        const int abeg = half * 90;
        #pragma unroll 6
        for (int a = abeg; a < abeg + 90; ++a) {
            float2 t  = trig[a];                               // uniform ds_read
            float pc  = fmaf(xS, t.x, fmaf(yS, -t.y, 255.5f));
            pc        = fmaxf(pc, 0.0f);
            int   fi  = (int)pc;                               // trunc==floor
            float w   = __builtin_amdgcn_fractf(pc);
            half2v hw = pack_w1(w);
            uint2  g  = xfh[(a << 9) + fi];
            a0 = __builtin_amdgcn_fdot2(hw, __builtin_bit_cast(half2v, g.x), a0, false);
            a1 = __builtin_amdgcn_fdot2(hw, __builtin_bit_cast(half2v, g.y), a1, false);
        }
    }

    if (half == 1) red[px] = make_float2(a0, a1);
    __syncthreads();
    if (half == 0) {
        const float2 r = red[px];
        const float msk = inc ? (kPI / (2.0f * (float)N_ANG)) : 0.0f;
        const int p = i * S_IMG + j;
        out[p]        = (a0 + r.x) * msk;
        out[NPIX + p] = (a1 + r.y) * msk;
    }
}

// ---------------------------------------------------------------------------
extern "C" void kernel_launch(void* const* d_in, const int* in_sizes, int n_in,
                              void* d_out, int out_size, void* d_ws, size_t ws_size,
                              hipStream_t stream) {
    const float* x   = (const float*)d_in[0];
    float*       out = (float*)d_out;
    unsigned*    xfh = (unsigned*)d_ws;  // 737,280 B

    ramp_filter_kernel<<<90, 512, 0, stream>>>(x, xfh);
    backproj_kernel<<<1024, 512, 0, stream>>>((const uint2*)xfh, out);
}